// Round 5
// baseline (356.217 us; speedup 1.0000x reference)
//
#include <hip/hip_runtime.h>
#include <math.h>

#define N_ROWS 32768
#define K_CODES 8192
#define DIM 64
#define CHUNKS 8
#define CPC (K_CODES / CHUNKS)   // 1024 codes per chunk
#define TILES (CPC / 32)         // 32 tiles of 32 codes

using half8  = __attribute__((ext_vector_type(8))) _Float16;
using f32x16 = __attribute__((ext_vector_type(16))) float;

// ---------------- ws layout ----------------
#define WS_W2     0          // float w2g[8192]          32 KB
#define WS_COUNTS 32768      // int counts[8192]         32 KB
#define WS_CSUM   65536      // float csum               16 B
#define WS_BEST   65552      // u64 best[32768]          256 KB
#define WS_WHL    327936     // _Float16 whl[8192][128]  2 MB (hi[64]|lo[64])

__device__ __forceinline__ void gload_lds16(const _Float16* g, _Float16* l) {
    __builtin_amdgcn_global_load_lds(
        (const __attribute__((address_space(1))) void*)g,
        (__attribute__((address_space(3))) void*)l, 16, 0, 0);
}

// ---------------- kernel 1: split + w2 + init best/counts/csum ----------------
__global__ __launch_bounds__(256) void vq_prep(const float* __restrict__ W,
                                               _Float16* __restrict__ whl,
                                               float* __restrict__ w2g,
                                               unsigned long long* __restrict__ best,
                                               int* __restrict__ counts,
                                               float* __restrict__ csum) {
    int g = blockIdx.x * 256 + threadIdx.x;   // 0 .. 524287
    int code = g >> 6, k = g & 63;
    float w = W[g];
    _Float16 h  = (_Float16)w;
    _Float16 lo = (_Float16)(w - (float)h);
    whl[(size_t)code * 128 + k]      = h;
    whl[(size_t)code * 128 + 64 + k] = lo;
    float s = w * w;
    #pragma unroll
    for (int off = 32; off; off >>= 1) s += __shfl_down(s, off);
    if (k == 0) w2g[code] = s;
    if (g < N_ROWS)  best[g] = ~0ULL;
    if (g < K_CODES) counts[g] = 0;
    if (g == 0)      *csum = 0.f;
}

// ---------------- kernel 2: MFMA scores + per-row argmin ----------------
// R3-proven double-buffer loop, 1 syncthreads/tile. 4 blocks/CU via CHUNKS=8.
__global__ __launch_bounds__(256, 4) void vq_mfma(const float* __restrict__ x,
                                                  const _Float16* __restrict__ whl,
                                                  const float* __restrict__ w2g,
                                                  unsigned long long* __restrict__ best) {
    __shared__ __align__(16) _Float16 lds[2][4096];   // 2 x 8KB

    const int t     = threadIdx.x;
    const int wv    = t >> 6;
    const int l     = t & 63;
    const int ln31  = l & 31;
    const int lhalf = l >> 5;
    const int chunk = blockIdx.x & (CHUNKS - 1);
    const int rblk  = blockIdx.x / CHUNKS;
    const int rowb  = rblk * 256 + wv * 64;
    const int cbase = chunk * CPC;

    // A fragments: 2 row groups, exact f16 hi/lo split
    half8 ahi0[4], alo0[4], ahi1[4], alo1[4];
    {
        const float* xr0 = x + (size_t)(rowb + ln31) * DIM + lhalf * 8;
        const float* xr1 = x + (size_t)(rowb + 32 + ln31) * DIM + lhalf * 8;
        #pragma unroll
        for (int kt = 0; kt < 4; ++kt) {
            float4 a0 = *(const float4*)(xr0 + kt * 16);
            float4 a1 = *(const float4*)(xr0 + kt * 16 + 4);
            float4 b0 = *(const float4*)(xr1 + kt * 16);
            float4 b1 = *(const float4*)(xr1 + kt * 16 + 4);
            float fa[8] = {a0.x, a0.y, a0.z, a0.w, a1.x, a1.y, a1.z, a1.w};
            float fb[8] = {b0.x, b0.y, b0.z, b0.w, b1.x, b1.y, b1.z, b1.w};
            #pragma unroll
            for (int j = 0; j < 8; ++j) {
                _Float16 h0 = (_Float16)fa[j];
                _Float16 h1 = (_Float16)fb[j];
                ahi0[kt][j] = h0; alo0[kt][j] = (_Float16)(fa[j] - (float)h0);
                ahi1[kt][j] = h1; alo1[kt][j] = (_Float16)(fb[j] - (float)h1);
            }
        }
    }

    // staging map: wave wv, instr p stages granules G = p*256 + wv*64 + lane
    // q = G>>6 = p*4+wv: kt=q>>1, hilo=q&1; src halves offset = (q&1)*64 + lhalf*8 + (q>>1)*16
    const _Float16* srcp[2];
    int ldsG[2];
    #pragma unroll
    for (int p = 0; p < 2; ++p) {
        int q = p * 4 + wv;
        srcp[p] = whl + (size_t)(cbase + ln31) * 128 + ((q & 1) * 8 + lhalf + 2 * (q >> 1)) * 8;
        ldsG[p] = (p * 256 + wv * 64) * 8;   // wave-uniform base (halves); HW adds lane*16B
    }

    float bv0[16], bv1[16];
    int   bi0[16], bi1[16];
    #pragma unroll
    for (int s2 = 0; s2 < 16; ++s2) { bv0[s2] = 3.4e38f; bv1[s2] = 3.4e38f; bi0[s2] = 0; bi1[s2] = 0; }

    // prologue: stage tile 0 into buf 0
    #pragma unroll
    for (int p = 0; p < 2; ++p) gload_lds16(srcp[p], &lds[0][0] + ldsG[p]);
    __syncthreads();

    const float* w2p = w2g + cbase + ln31;
    int cur = 0;

    for (int tile = 0; tile < TILES; ++tile) {
        // prefetch next tile into buf^1 (codes advance by 32 -> +4096 halves)
        if (tile < TILES - 1) {
            #pragma unroll
            for (int p = 0; p < 2; ++p)
                gload_lds16(srcp[p] + (tile + 1) * 4096, &lds[0][0] + (cur ^ 1) * 4096 + ldsG[p]);
        }
        const float w2v = w2p[tile * 32];
        const _Float16* lb = &lds[0][0] + cur * 4096;

        f32x16 acc0 = {}, acc1 = {};
        __builtin_amdgcn_s_setprio(1);
        #pragma unroll
        for (int kt = 0; kt < 4; ++kt) {
            half8 bh = *(const half8*)(lb + ((kt * 2 + 0) * 64 + l) * 8);
            half8 bl = *(const half8*)(lb + ((kt * 2 + 1) * 64 + l) * 8);
            acc0 = __builtin_amdgcn_mfma_f32_32x32x16_f16(ahi0[kt], bh, acc0, 0, 0, 0);
            acc1 = __builtin_amdgcn_mfma_f32_32x32x16_f16(ahi1[kt], bh, acc1, 0, 0, 0);
            acc0 = __builtin_amdgcn_mfma_f32_32x32x16_f16(alo0[kt], bh, acc0, 0, 0, 0);
            acc1 = __builtin_amdgcn_mfma_f32_32x32x16_f16(alo1[kt], bh, acc1, 0, 0, 0);
            acc0 = __builtin_amdgcn_mfma_f32_32x32x16_f16(ahi0[kt], bl, acc0, 0, 0, 0);
            acc1 = __builtin_amdgcn_mfma_f32_32x32x16_f16(ahi1[kt], bl, acc1, 0, 0, 0);
        }
        __builtin_amdgcn_s_setprio(0);

        const int cc = cbase + tile * 32 + ln31;
        #pragma unroll
        for (int s2 = 0; s2 < 16; ++s2) {
            float sA = fmaf(-2.f, acc0[s2], w2v);
            float sB = fmaf(-2.f, acc1[s2], w2v);
            if (sA < bv0[s2]) { bv0[s2] = sA; bi0[s2] = cc; }
            if (sB < bv1[s2]) { bv1[s2] = sB; bi1[s2] = cc; }
        }
        __syncthreads();   // all reads of buf `cur` done; prefetch into cur^1 drained
        cur ^= 1;
    }

    // per-row reduce across the 32 lanes sharing each row, then global merge
    #pragma unroll
    for (int rg = 0; rg < 2; ++rg) {
        #pragma unroll
        for (int s2 = 0; s2 < 16; ++s2) {
            float fv = rg ? bv1[s2] : bv0[s2];
            int   iv = rg ? bi1[s2] : bi0[s2];
            unsigned uk = __float_as_uint(fv);
            uk = (uk >> 31) ? ~uk : (uk | 0x80000000u);   // monotone float->uint
            unsigned long long key = ((unsigned long long)uk << 32) | (unsigned)iv;
            #pragma unroll
            for (int off = 16; off; off >>= 1) {
                unsigned long long o = __shfl_xor(key, off);
                key = (o < key) ? o : key;
            }
            if (ln31 == 0) {
                int rl = (s2 & 3) + 8 * (s2 >> 2) + 4 * lhalf;   // C/D row map (m74/m101)
                atomicMin(&best[rowb + rg * 32 + rl], key);
            }
        }
    }
}

// ---------------- kernel 3: gather z, commitment partial, histogram ----------------
__global__ __launch_bounds__(256) void vq_gather(const float* __restrict__ x,
                                                 const float* __restrict__ W,
                                                 const unsigned long long* __restrict__ best,
                                                 float* __restrict__ zout,
                                                 int* __restrict__ counts,
                                                 float* __restrict__ csum) {
    int t   = threadIdx.x;
    int row = blockIdx.x * 64 + (t >> 2);
    int seg = t & 3;
    int idx = (int)(best[row] & 0xFFFFFFFFULL);
    if (seg == 0) atomicAdd(&counts[idx], 1);
    const float* wrow = W    + (size_t)idx * DIM + seg * 16;
    const float* xrow = x    + (size_t)row * DIM + seg * 16;
    float*       zrow = zout + (size_t)row * DIM + seg * 16;
    float local = 0.f;
    #pragma unroll
    for (int j = 0; j < 16; j += 4) {
        float4 wv = *(const float4*)(wrow + j);
        float4 xv = *(const float4*)(xrow + j);
        *(float4*)(zrow + j) = wv;
        float dx = wv.x - xv.x, dy = wv.y - xv.y, dz = wv.z - xv.z, dw = wv.w - xv.w;
        local += dx * dx + dy * dy + dz * dz + dw * dw;
    }
    #pragma unroll
    for (int off = 32; off; off >>= 1) local += __shfl_down(local, off);
    if ((t & 63) == 0) atomicAdd(csum, local);
}

// ---------------- kernel 4: finalize scalars ----------------
__global__ __launch_bounds__(256) void vq_final(const int* __restrict__ counts,
                                                const float* __restrict__ csum,
                                                float* __restrict__ out3) {
    __shared__ float sh[4];
    float e = 0.f;
    for (int i = threadIdx.x; i < K_CODES; i += 256) {
        float p = (float)counts[i] * (1.0f / N_ROWS);
        e += p * logf(p + 1e-10f);
    }
    #pragma unroll
    for (int off = 32; off; off >>= 1) e += __shfl_down(e, off);
    if ((threadIdx.x & 63) == 0) sh[threadIdx.x >> 6] = e;
    __syncthreads();
    if (threadIdx.x == 0) {
        float tot = sh[0] + sh[1] + sh[2] + sh[3];
        out3[0] = 0.f;
        out3[1] = csum[0] * (1.0f / ((float)N_ROWS * DIM));
        out3[2] = expf(-tot);
    }
}

extern "C" void kernel_launch(void* const* d_in, const int* in_sizes, int n_in,
                              void* d_out, int out_size, void* d_ws, size_t ws_size,
                              hipStream_t stream) {
    (void)in_sizes; (void)n_in; (void)out_size; (void)ws_size;
    const float* x = (const float*)d_in[0];
    const float* W = (const float*)d_in[1];
    float* zout = (float*)d_out;
    float* out3 = (float*)d_out + (size_t)N_ROWS * DIM;

    float*              w2g    = (float*)((char*)d_ws + WS_W2);
    int*                counts = (int*)((char*)d_ws + WS_COUNTS);
    float*              csum   = (float*)((char*)d_ws + WS_CSUM);
    unsigned long long* best   = (unsigned long long*)((char*)d_ws + WS_BEST);
    _Float16*           whl    = (_Float16*)((char*)d_ws + WS_WHL);

    vq_prep  <<<K_CODES * DIM / 256,     256, 0, stream>>>(W, whl, w2g, best, counts, csum);
    vq_mfma  <<<(N_ROWS / 256) * CHUNKS, 256, 0, stream>>>(x, whl, w2g, best);
    vq_gather<<<N_ROWS / 64,             256, 0, stream>>>(x, W, best, zout, counts, csum);
    vq_final <<<1,                       256, 0, stream>>>(counts, csum, out3);
}

// Round 6
// 156.446 us; speedup vs baseline: 2.2769x; 2.2769x over previous
//
#include <hip/hip_runtime.h>
#include <math.h>

#define N_ROWS 32768
#define K_CODES 8192
#define DIM 64
#define CHUNKS 4
#define CPC (K_CODES / CHUNKS)   // 2048 codes per chunk
#define TILES (CPC / 32)         // 64 tiles of 32 codes

using half8  = __attribute__((ext_vector_type(8))) _Float16;
using f32x16 = __attribute__((ext_vector_type(16))) float;

// ---------------- ws layout ----------------
#define WS_W2     0          // float w2g[8192]          32 KB
#define WS_COUNTS 32768      // int counts[8192]         32 KB
#define WS_CSUM   65536      // float csum               16 B
#define WS_BEST   65552      // u64 best[32768]          256 KB
#define WS_WHL    327936     // _Float16 whl[8192][128]  2 MB (hi[64]|lo[64])

__device__ __forceinline__ void gload_lds16(const _Float16* g, _Float16* l) {
    __builtin_amdgcn_global_load_lds(
        (const __attribute__((address_space(1))) void*)g,
        (__attribute__((address_space(3))) void*)l, 16, 0, 0);
}

// ---------------- kernel 1: split + w2 + init best/counts/csum ----------------
__global__ __launch_bounds__(256) void vq_prep(const float* __restrict__ W,
                                               _Float16* __restrict__ whl,
                                               float* __restrict__ w2g,
                                               unsigned long long* __restrict__ best,
                                               int* __restrict__ counts,
                                               float* __restrict__ csum) {
    int g = blockIdx.x * 256 + threadIdx.x;   // 0 .. 524287
    int code = g >> 6, k = g & 63;
    float w = W[g];
    _Float16 h  = (_Float16)w;
    _Float16 lo = (_Float16)(w - (float)h);
    whl[(size_t)code * 128 + k]      = h;
    whl[(size_t)code * 128 + 64 + k] = lo;
    float s = w * w;
    #pragma unroll
    for (int off = 32; off; off >>= 1) s += __shfl_down(s, off);
    if (k == 0) w2g[code] = s;
    if (g < N_ROWS)  best[g] = ~0ULL;
    if (g < K_CODES) counts[g] = 0;
    if (g == 0)      *csum = 0.f;
}

// ---------------- kernel 2: MFMA scores + per-row argmin ----------------
// R3-proven loop, 1 row-group/wave (32 rows) -> ~105 VGPR -> 4 blocks/CU, no spill.
__global__ __launch_bounds__(256, 4) void vq_mfma(const float* __restrict__ x,
                                                  const _Float16* __restrict__ whl,
                                                  const float* __restrict__ w2g,
                                                  unsigned long long* __restrict__ best) {
    __shared__ __align__(16) _Float16 lds[2][4096];   // 2 x 8KB

    const int t     = threadIdx.x;
    const int wv    = t >> 6;
    const int l     = t & 63;
    const int ln31  = l & 31;
    const int lhalf = l >> 5;
    const int chunk = blockIdx.x & (CHUNKS - 1);
    const int rblk  = blockIdx.x / CHUNKS;
    const int rowb  = rblk * 128 + wv * 32;    // wave owns 32 rows
    const int cbase = chunk * CPC;

    // A fragments: exact f16 hi/lo split of this lane's row slice
    half8 ahi[4], alo[4];
    {
        const float* xr = x + (size_t)(rowb + ln31) * DIM + lhalf * 8;
        #pragma unroll
        for (int kt = 0; kt < 4; ++kt) {
            float4 a0 = *(const float4*)(xr + kt * 16);
            float4 a1 = *(const float4*)(xr + kt * 16 + 4);
            float fa[8] = {a0.x, a0.y, a0.z, a0.w, a1.x, a1.y, a1.z, a1.w};
            #pragma unroll
            for (int j = 0; j < 8; ++j) {
                _Float16 h = (_Float16)fa[j];
                ahi[kt][j] = h;
                alo[kt][j] = (_Float16)(fa[j] - (float)h);
            }
        }
    }

    // staging map: wave wv, instr p stages granules G = p*256 + wv*64 + lane
    // q = G>>6 = p*4+wv: kt=q>>1, hilo=q&1; LDS linear dest = G*16B (HW adds lane*16)
    const _Float16* srcp[2];
    int ldsG[2];
    #pragma unroll
    for (int p = 0; p < 2; ++p) {
        int q = p * 4 + wv;
        srcp[p] = whl + (size_t)(cbase + ln31) * 128 + ((q & 1) * 8 + lhalf + 2 * (q >> 1)) * 8;
        ldsG[p] = (p * 256 + wv * 64) * 8;   // wave-uniform base (halves)
    }

    float bv[16];
    int   bi[16];
    #pragma unroll
    for (int s2 = 0; s2 < 16; ++s2) { bv[s2] = 3.4e38f; bi[s2] = 0; }

    // prologue: stage tile 0 into buf 0
    #pragma unroll
    for (int p = 0; p < 2; ++p) gload_lds16(srcp[p], &lds[0][0] + ldsG[p]);
    __syncthreads();

    const float* w2p = w2g + cbase + ln31;
    int cur = 0;

    for (int tile = 0; tile < TILES; ++tile) {
        if (tile < TILES - 1) {
            #pragma unroll
            for (int p = 0; p < 2; ++p)
                gload_lds16(srcp[p] + (tile + 1) * 4096, &lds[0][0] + (cur ^ 1) * 4096 + ldsG[p]);
        }
        const float w2v = w2p[tile * 32];
        const _Float16* lb = &lds[0][0] + cur * 4096;

        f32x16 acc = {};
        __builtin_amdgcn_s_setprio(1);
        #pragma unroll
        for (int kt = 0; kt < 4; ++kt) {
            half8 bh = *(const half8*)(lb + ((kt * 2 + 0) * 64 + l) * 8);
            half8 bl = *(const half8*)(lb + ((kt * 2 + 1) * 64 + l) * 8);
            acc = __builtin_amdgcn_mfma_f32_32x32x16_f16(ahi[kt], bh, acc, 0, 0, 0);
            acc = __builtin_amdgcn_mfma_f32_32x32x16_f16(alo[kt], bh, acc, 0, 0, 0);
            acc = __builtin_amdgcn_mfma_f32_32x32x16_f16(ahi[kt], bl, acc, 0, 0, 0);
        }
        __builtin_amdgcn_s_setprio(0);

        const int cc = cbase + tile * 32 + ln31;
        #pragma unroll
        for (int s2 = 0; s2 < 16; ++s2) {
            float sA = fmaf(-2.f, acc[s2], w2v);
            if (sA < bv[s2]) { bv[s2] = sA; bi[s2] = cc; }
        }
        __syncthreads();   // reads of buf `cur` done; prefetch into cur^1 drained
        cur ^= 1;
    }

    // per-row reduce across the 32 lanes sharing each row, then global merge
    #pragma unroll
    for (int s2 = 0; s2 < 16; ++s2) {
        unsigned uk = __float_as_uint(bv[s2]);
        uk = (uk >> 31) ? ~uk : (uk | 0x80000000u);   // monotone float->uint
        unsigned long long key = ((unsigned long long)uk << 32) | (unsigned)bi[s2];
        #pragma unroll
        for (int off = 16; off; off >>= 1) {
            unsigned long long o = __shfl_xor(key, off);
            key = (o < key) ? o : key;
        }
        if (ln31 == 0) {
            int rl = (s2 & 3) + 8 * (s2 >> 2) + 4 * lhalf;   // C/D row map (m74/m101)
            atomicMin(&best[rowb + rl], key);
        }
    }
}

// ---------------- kernel 3: gather z, commitment partial, histogram ----------------
__global__ __launch_bounds__(256) void vq_gather(const float* __restrict__ x,
                                                 const float* __restrict__ W,
                                                 const unsigned long long* __restrict__ best,
                                                 float* __restrict__ zout,
                                                 int* __restrict__ counts,
                                                 float* __restrict__ csum) {
    int t   = threadIdx.x;
    int row = blockIdx.x * 64 + (t >> 2);
    int seg = t & 3;
    int idx = (int)(best[row] & 0xFFFFFFFFULL);
    if (seg == 0) atomicAdd(&counts[idx], 1);
    const float* wrow = W    + (size_t)idx * DIM + seg * 16;
    const float* xrow = x    + (size_t)row * DIM + seg * 16;
    float*       zrow = zout + (size_t)row * DIM + seg * 16;
    float local = 0.f;
    #pragma unroll
    for (int j = 0; j < 16; j += 4) {
        float4 wv = *(const float4*)(wrow + j);
        float4 xv = *(const float4*)(xrow + j);
        *(float4*)(zrow + j) = wv;
        float dx = wv.x - xv.x, dy = wv.y - xv.y, dz = wv.z - xv.z, dw = wv.w - xv.w;
        local += dx * dx + dy * dy + dz * dz + dw * dw;
    }
    #pragma unroll
    for (int off = 32; off; off >>= 1) local += __shfl_down(local, off);
    if ((t & 63) == 0) atomicAdd(csum, local);
}

// ---------------- kernel 4: finalize scalars ----------------
__global__ __launch_bounds__(256) void vq_final(const int* __restrict__ counts,
                                                const float* __restrict__ csum,
                                                float* __restrict__ out3) {
    __shared__ float sh[4];
    float e = 0.f;
    for (int i = threadIdx.x; i < K_CODES; i += 256) {
        float p = (float)counts[i] * (1.0f / N_ROWS);
        e += p * logf(p + 1e-10f);
    }
    #pragma unroll
    for (int off = 32; off; off >>= 1) e += __shfl_down(e, off);
    if ((threadIdx.x & 63) == 0) sh[threadIdx.x >> 6] = e;
    __syncthreads();
    if (threadIdx.x == 0) {
        float tot = sh[0] + sh[1] + sh[2] + sh[3];
        out3[0] = 0.f;
        out3[1] = csum[0] * (1.0f / ((float)N_ROWS * DIM));
        out3[2] = expf(-tot);
    }
}

extern "C" void kernel_launch(void* const* d_in, const int* in_sizes, int n_in,
                              void* d_out, int out_size, void* d_ws, size_t ws_size,
                              hipStream_t stream) {
    (void)in_sizes; (void)n_in; (void)out_size; (void)ws_size;
    const float* x = (const float*)d_in[0];
    const float* W = (const float*)d_in[1];
    float* zout = (float*)d_out;
    float* out3 = (float*)d_out + (size_t)N_ROWS * DIM;

    float*              w2g    = (float*)((char*)d_ws + WS_W2);
    int*                counts = (int*)((char*)d_ws + WS_COUNTS);
    float*              csum   = (float*)((char*)d_ws + WS_CSUM);
    unsigned long long* best   = (unsigned long long*)((char*)d_ws + WS_BEST);
    _Float16*           whl    = (_Float16*)((char*)d_ws + WS_WHL);

    vq_prep  <<<K_CODES * DIM / 256,     256, 0, stream>>>(W, whl, w2g, best, counts, csum);
    vq_mfma  <<<(N_ROWS / 128) * CHUNKS, 256, 0, stream>>>(x, whl, w2g, best);
    vq_gather<<<N_ROWS / 64,             256, 0, stream>>>(x, W, best, zout, counts, csum);
    vq_final <<<1,                       256, 0, stream>>>(counts, csum, out3);
}